// Round 11
// baseline (99.449 us; speedup 1.0000x reference)
//
#include <hip/hip_runtime.h>
#include <hip/hip_fp16.h>

// Problem constants (fixed by reference): B=512, F=8, D=4, R=32, U=64
#define NB 512
#define NF 8
#define ND 4
#define NR 32
#define NU 64
#define G  4   // batches (b) per wave (R15-proven)

typedef float f32x4 __attribute__((ext_vector_type(4)));
typedef unsigned u32x4 __attribute__((ext_vector_type(4)));
typedef _Float16 f16x8 __attribute__((ext_vector_type(8)));

// ---- f16 packed math, inline asm (PROVEN R14-R21: absmax 0.25). VOP3P
// one-SGPR-source via "s" constraint (proven R11). Asm opaque to optimizer
// (R9: native vector ops get reassociated and break chain numerics).
__device__ inline unsigned pkmul_h(unsigned a, unsigned s) {
    unsigned d;
    asm("v_pk_mul_f16 %0, %1, %2" : "=v"(d) : "v"(a), "s"(s));
    return d;
}
__device__ inline unsigned pkfma_h(unsigned a, unsigned s, unsigned c) {
    unsigned d;
    asm("v_pk_fma_f16 %0, %1, %2, %3" : "=v"(d) : "v"(a), "s"(s), "v"(c));
    return d;
}

// f32 pair -> packed f16 word, RTZ (v_cvt_pkrtz_f16_f32). PROVEN R14-R21.
__device__ inline unsigned pkrtz(float a, float b) {
    auto h = __builtin_amdgcn_cvt_pkrtz(a, b);
    static_assert(sizeof(h) == 4, "cvt_pkrtz must return 32-bit");
    return __builtin_bit_cast(unsigned, h);
}

// f32 pair -> packed f16 word, RNE (K pre-pass; K deserves round-nearest)
__device__ inline unsigned h2pack(float a, float b) {
    unsigned ha = (unsigned)__half_as_ushort(__float2half(a));
    unsigned hb = (unsigned)__half_as_ushort(__float2half(b));
    return ha | (hb << 16);
}

// wave-uniform u32 -> SGPR (readfirstlane; value unchanged)
__device__ inline unsigned rfl_u(unsigned v) {
    return (unsigned)__builtin_amdgcn_readfirstlane((int)v);
}

// ---------------------------------------------------------------------------
// Pre-pass (R17-R21-proven split, ~5us): 512 blocks (u split 16/block).
//   K3h u32 index = (u*8+f)*2048 + (q*4+jp)*128 + (I*16+c)*4 + d
//   word = half2( K[d][e_par0], K[d][e_par1] ),  e = 256q+64jp+32par+16I+c
// ---------------------------------------------------------------------------
__global__ __launch_bounds__(256) void tr_k3h22(const float* __restrict__ K,
                                                unsigned* __restrict__ K3h) {
    __shared__ float lds[256 * 20];   // rows (d*64+s) x 16 u, pad to 20
    const int t   = threadIdx.x;
    const int bid = blockIdx.x;
    const int uq = bid & 3, jp = (bid >> 2) & 3, q = (bid >> 4) & 3, f = bid >> 6;
    const int u0 = uq * 16;

    {   // read phase: rows r = d*64 + s, 16 floats of u each
        const int rr = t >> 2, col4 = (t & 3) * 4;
#pragma unroll
        for (int i = 0; i < 4; ++i) {
            int r = i * 64 + rr;              // 0..255
            int d = r >> 6, s = r & 63;
            int e = q * 256 + jp * 64 + s;
            f32x4 v = *(const f32x4*)(K + ((size_t)((d << 10) + e) << 9)
                                        + (f << 6) + u0 + col4);
            *(f32x4*)(lds + r * 20 + col4) = v;
        }
    }
    __syncthreads();
    {   // write phase: per u_l, f16-pair emit (8B per thread-iter)
        const int u_l = t >> 4, lane16 = t & 15;  // u_l 0..15
        unsigned* dst = K3h + ((size_t)((u0 + u_l) * 8 + f) << 11)
                            + ((q * 4 + jp) << 7);
#pragma unroll
        for (int g2 = 0; g2 < 4; ++g2) {
            int idx4 = lane16 + g2 * 16;      // 0..63
            int dh = idx4 & 1, Ic = idx4 >> 1;  // Ic = I*16+c in 0..31
            int d0 = dh * 2;
            float v0 = lds[(d0 * 64 + 0  + Ic) * 20 + u_l];   // d0, par0
            float v1 = lds[(d0 * 64 + 32 + Ic) * 20 + u_l];   // d0, par1
            float v2 = lds[((d0 + 1) * 64 + 0  + Ic) * 20 + u_l];
            float v3 = lds[((d0 + 1) * 64 + 32 + Ic) * 20 + u_l];
            uint2 wv; wv.x = h2pack(v0, v1); wv.y = h2pack(v2, v3);
            *(uint2*)(dst + idx4 * 2) = wv;   // words (Ic*4+2dh), (+1)
        }
    }
}

// ---------------------------------------------------------------------------
// Main R22 = R21's ops EXACTLY (bit-identical values/addresses) with ONE
// concept: per-wave ILP. Evidence: R19 doubled occupancy at VGPR 32 ->
// flat; (waves x regs) curve flat between (2.5w,52r) and (5w,32r); no
// counter saturated -> per-wave dependency serialization is the 42us floor.
// At 52 VGPR the compiler g-serializes the MFMA phase (4 chained
// read->wait->MFMA->write round-trips per f).
// Changes: (a) waves_per_eu(4,4) -> (2) min-only: allocator freed to ~128
// VGPR (the (4,4) cap was R10's anti-spill tool; now deliberately spent).
// (b) MFMA phase batches ALL 8 B-frag reads (all g) before any MFMA: one
// lgkm drain instead of 4 chained; then per-g {4 MFMA, 8 pkrtz, 4 writes}.
// g-slots are disjoint (nb = Nb0 + g*2048) so read/write reorder across g
// is safe; fence still orders f's writes before f+1's reads.
// Discriminators: VGPR 52 -> ~100-130 (knob engaged); absmax EXACTLY 0.25;
// if ILP-bound: main 33-37us; if flat ~42: ILP not the binder -> swizzle
// probe next, then declare floor. WRITE_SIZE ~1MB (spill tripwire);
// FETCH ~2710KB; Occupancy ~31 (LDS-pinned, unchanged).
// ---------------------------------------------------------------------------
__global__ __launch_bounds__(128)
__attribute__((amdgpu_waves_per_eu(2)))
void tr_main22(const float* __restrict__ X,
               const unsigned* __restrict__ K3h,
               float* __restrict__ out) {
    const int tid  = threadIdx.x;
    const int w    = __builtin_amdgcn_readfirstlane(tid >> 6);  // wave id, SGPR
    const int lane = tid & 63;
    const int c    = lane & 15;
    const int q    = lane >> 4;
    const int u      = blockIdx.x & 63;               // u-minor (R3/R7-proven)
    const int bgroup = blockIdx.x >> 6;               // 0..63
    const int b0     = ((bgroup << 1) + w) * G;       // SGPR-computed

    __shared__ __attribute__((aligned(16))) char lds[2 * G * 2048];
    char* Nb0 = lds + w * (G * 2048);

    // identity B-frags for f=0: B[k=8q+j][n=c(+16)]; f16 1.0 = 0x3C00 exact
    f16x8 idf0, idf1;
#pragma unroll
    for (int jj = 0; jj < 8; ++jj) {
        idf0[jj] = (8 * q + jj == c) ? (_Float16)1.0f : (_Float16)0.0f;
        idf1[jj] = (8 * q + jj == 16 + c) ? (_Float16)1.0f : (_Float16)0.0f;
    }

    const unsigned* Kt = K3h + ((size_t)u << 14) + (q << 9) + (c << 2);
    const f32x4 z = {0.f, 0.f, 0.f, 0.f};

#pragma unroll
    for (int f = 0; f < NF; ++f) {
        const unsigned* Kf = Kt + (f << 11);

        // ---- X broadcasts (proven): VMEM load + pkrtz + rfl -> SGPRs ----
        unsigned xdd[G][4];
#pragma unroll
        for (int g = 0; g < G; ++g) {
            const f32x4 xv = *(const f32x4*)(X + ((b0 + g) << 5) + (f << 2));
#pragma unroll
            for (int d = 0; d < 4; ++d)
                xdd[g][d] = rfl_u(pkrtz(xv[d], xv[d]));
        }

        // ---- A-phase: jp-outer, g-inner; 1-deep staging prefetch ----
        u32x4 A0u[G], A1u[G];
        u32x4 s0 = *(const u32x4*)(Kf + 0);       // (jp=0, I=0)
        u32x4 s1 = *(const u32x4*)(Kf + 64);      // (jp=0, I=1)
#pragma unroll
        for (int jp = 0; jp < 4; ++jp) {
            u32x4 c0 = s0, c1 = s1;
            if (jp < 3) {
                const unsigned* pn = Kf + ((jp + 1) << 7);
                s0 = *(const u32x4*)(pn + 0);
                s1 = *(const u32x4*)(pn + 64);
            }
#pragma unroll
            for (int g = 0; g < G; ++g) {
                {   // I = 0: A-word = (T[e_par0], T[e_par1]) f16
                    unsigned tv = pkmul_h(c0[0], xdd[g][0]);
                    tv = pkfma_h(c0[1], xdd[g][1], tv);
                    tv = pkfma_h(c0[2], xdd[g][2], tv);
                    tv = pkfma_h(c0[3], xdd[g][3], tv);
                    A0u[g][jp] = tv;
                }
                {   // I = 1
                    unsigned tv = pkmul_h(c1[0], xdd[g][0]);
                    tv = pkfma_h(c1[1], xdd[g][1], tv);
                    tv = pkfma_h(c1[2], xdd[g][2], tv);
                    tv = pkfma_h(c1[3], xdd[g][3], tv);
                    A1u[g][jp] = tv;
                }
            }
        }

        // ---- MFMA phase, R22-restructured: batch ALL B-frag reads first
        //      (8 ds_read_b128, one lgkm drain), then per-g compute+write ----
        f16x8 b0v[G], b1v[G];
        if (f == 0) {
#pragma unroll
            for (int g = 0; g < G; ++g) { b0v[g] = idf0; b1v[g] = idf1; }
        } else {
#pragma unroll
            for (int g = 0; g < G; ++g) {
                const char* nb = Nb0 + (g << 11);
                b0v[g] = *(const f16x8*)(nb + (((q << 5) | c) << 4));
                b1v[g] = *(const f16x8*)(nb + (((q << 5) | c) << 4) + 256);
            }
        }

#pragma unroll
        for (int g = 0; g < G; ++g) {
            char* nb = Nb0 + (g << 11);
            f16x8 A0 = __builtin_bit_cast(f16x8, A0u[g]);
            f16x8 A1 = __builtin_bit_cast(f16x8, A1u[g]);

            if (f < NF - 1) {
                f32x4 c00 = __builtin_amdgcn_mfma_f32_16x16x32_f16(A0, b0v[g], z, 0, 0, 0);
                f32x4 c01 = __builtin_amdgcn_mfma_f32_16x16x32_f16(A0, b1v[g], z, 0, 0, 0);
                f32x4 c10 = __builtin_amdgcn_mfma_f32_16x16x32_f16(A1, b0v[g], z, 0, 0, 0);
                f32x4 c11 = __builtin_amdgcn_mfma_f32_16x16x32_f16(A1, b1v[g], z, 0, 0, 0);
                // writeback N' (f16) for next f
#pragma unroll
                for (int I = 0; I < 2; ++I)
#pragma unroll
                    for (int J = 0; J < 2; ++J) {
                        f32x4 a = (I == 0) ? (J == 0 ? c00 : c01)
                                           : (J == 0 ? c10 : c11);
                        unsigned lo = pkrtz(a[0], a[1]);
                        unsigned hi = pkrtz(a[2], a[3]);
                        uint2 val; val.x = lo; val.y = hi;
                        // slot(p = 2I + (q>>1), n = 16J + c), byte +8*(q&1)
                        *(uint2*)(nb + (((((I << 1) | (q >> 1)) << 5) | (J << 4) | c) << 4)
                                     + ((q & 1) << 3)) = val;
                    }
            } else {
                // last step: only diagonal tiles feed the trace
                f32x4 c00 = __builtin_amdgcn_mfma_f32_16x16x32_f16(A0, b0v[g], z, 0, 0, 0);
                f32x4 c11 = __builtin_amdgcn_mfma_f32_16x16x32_f16(A1, b1v[g], z, 0, 0, 0);
                f32x4 t4 = c00 + c11;
                int ri = c & 3;
                float s = (ri == 0) ? t4[0] : (ri == 1) ? t4[1]
                        : (ri == 2) ? t4[2] : t4[3];
                s = ((c >> 2) == q) ? s : 0.f;
#pragma unroll
                for (int m = 32; m >= 1; m >>= 1) s += __shfl_xor(s, m, 64);
                if (lane == 0) out[((b0 + g) << 6) + u] = s;
            }
        }
        // Compiler memory fence: this-f LDS writes must precede next-f LDS
        // reads in program order (HW DS pipe is in-order per wave; only the
        // compiler could break it). Zero instructions emitted.
        asm volatile("" ::: "memory");
    }
}

extern "C" void kernel_launch(void* const* d_in, const int* in_sizes, int n_in,
                              void* d_out, int out_size, void* d_ws, size_t ws_size,
                              hipStream_t stream) {
    (void)in_sizes; (void)n_in; (void)out_size; (void)ws_size;
    const float* X = (const float*)d_in[0];   // [512][8][4]
    const float* K = (const float*)d_in[1];   // [4][32][32][8][64]
    float* out = (float*)d_out;               // [512][64]
    unsigned* K3h = (unsigned*)d_ws;          // 4 MB, f16 par-pair words

    hipLaunchKernelGGL(tr_k3h22, dim3(512), dim3(256), 0, stream, K, K3h);
    hipLaunchKernelGGL(tr_main22, dim3(4096), dim3(128), 0, stream, X, K3h, out);
}

// Round 12
// 96.209 us; speedup vs baseline: 1.0337x; 1.0337x over previous
//
#include <hip/hip_runtime.h>
#include <hip/hip_fp16.h>

// Problem constants (fixed by reference): B=512, F=8, D=4, R=32, U=64
#define NB 512
#define NF 8
#define ND 4
#define NR 32
#define NU 64
#define G  4   // batches (b) per wave (R15-proven)

typedef float f32x4 __attribute__((ext_vector_type(4)));
typedef unsigned u32x4 __attribute__((ext_vector_type(4)));
typedef _Float16 f16x8 __attribute__((ext_vector_type(8)));

// ---- f16 packed math, inline asm (PROVEN R14-R22: absmax 0.25). VOP3P
// one-SGPR-source via "s" constraint (proven R11). Asm opaque to optimizer
// (R9: native vector ops get reassociated and break chain numerics).
__device__ inline unsigned pkmul_h(unsigned a, unsigned s) {
    unsigned d;
    asm("v_pk_mul_f16 %0, %1, %2" : "=v"(d) : "v"(a), "s"(s));
    return d;
}
__device__ inline unsigned pkfma_h(unsigned a, unsigned s, unsigned c) {
    unsigned d;
    asm("v_pk_fma_f16 %0, %1, %2, %3" : "=v"(d) : "v"(a), "s"(s), "v"(c));
    return d;
}

// f32 pair -> packed f16 word, RTZ (v_cvt_pkrtz_f16_f32). PROVEN R14-R22.
__device__ inline unsigned pkrtz(float a, float b) {
    auto h = __builtin_amdgcn_cvt_pkrtz(a, b);
    static_assert(sizeof(h) == 4, "cvt_pkrtz must return 32-bit");
    return __builtin_bit_cast(unsigned, h);
}

// f32 pair -> packed f16 word, RNE (K pre-pass; K deserves round-nearest)
__device__ inline unsigned h2pack(float a, float b) {
    unsigned ha = (unsigned)__half_as_ushort(__float2half(a));
    unsigned hb = (unsigned)__half_as_ushort(__float2half(b));
    return ha | (hb << 16);
}

// wave-uniform u32 -> SGPR (readfirstlane; value unchanged)
__device__ inline unsigned rfl_u(unsigned v) {
    return (unsigned)__builtin_amdgcn_readfirstlane((int)v);
}

// ---------------------------------------------------------------------------
// Pre-pass (R17-R22-proven split, ~5us): 512 blocks (u split 16/block).
//   K3h u32 index = (u*8+f)*2048 + (q*4+jp)*128 + (I*16+c)*4 + d
//   word = half2( K[d][e_par0], K[d][e_par1] ),  e = 256q+64jp+32par+16I+c
// ---------------------------------------------------------------------------
__global__ __launch_bounds__(256) void tr_k3h23(const float* __restrict__ K,
                                                unsigned* __restrict__ K3h) {
    __shared__ float lds[256 * 20];   // rows (d*64+s) x 16 u, pad to 20
    const int t   = threadIdx.x;
    const int bid = blockIdx.x;
    const int uq = bid & 3, jp = (bid >> 2) & 3, q = (bid >> 4) & 3, f = bid >> 6;
    const int u0 = uq * 16;

    {   // read phase: rows r = d*64 + s, 16 floats of u each
        const int rr = t >> 2, col4 = (t & 3) * 4;
#pragma unroll
        for (int i = 0; i < 4; ++i) {
            int r = i * 64 + rr;              // 0..255
            int d = r >> 6, s = r & 63;
            int e = q * 256 + jp * 64 + s;
            f32x4 v = *(const f32x4*)(K + ((size_t)((d << 10) + e) << 9)
                                        + (f << 6) + u0 + col4);
            *(f32x4*)(lds + r * 20 + col4) = v;
        }
    }
    __syncthreads();
    {   // write phase: per u_l, f16-pair emit (8B per thread-iter)
        const int u_l = t >> 4, lane16 = t & 15;  // u_l 0..15
        unsigned* dst = K3h + ((size_t)((u0 + u_l) * 8 + f) << 11)
                            + ((q * 4 + jp) << 7);
#pragma unroll
        for (int g2 = 0; g2 < 4; ++g2) {
            int idx4 = lane16 + g2 * 16;      // 0..63
            int dh = idx4 & 1, Ic = idx4 >> 1;  // Ic = I*16+c in 0..31
            int d0 = dh * 2;
            float v0 = lds[(d0 * 64 + 0  + Ic) * 20 + u_l];   // d0, par0
            float v1 = lds[(d0 * 64 + 32 + Ic) * 20 + u_l];   // d0, par1
            float v2 = lds[((d0 + 1) * 64 + 0  + Ic) * 20 + u_l];
            float v3 = lds[((d0 + 1) * 64 + 32 + Ic) * 20 + u_l];
            uint2 wv; wv.x = h2pack(v0, v1); wv.y = h2pack(v2, v3);
            *(uint2*)(dst + idx4 * 2) = wv;   // words (Ic*4+2dh), (+1)
        }
    }
}

// ---------------------------------------------------------------------------
// Main R23 = R21's ops EXACTLY (same instructions, addresses, values ->
// absmax must stay 0.25) with ONE concept: FULL cross-f software pipeline.
// Triangulated from 3 nulls: R17 (2/12 loads prefetched: null), R19 (2x
// occupancy: null), R22 (B-read batch + freed VGPR budget: allocator
// REFUSED more regs, 44). Diagnosis: the per-f memory fence (required for
// LDS write->read ordering) also traps the 12 global loads (8 K-words, 4
// X-vecs) of the next f, exposing a ~200cy L2 wall at every f start and
// preventing the compiler from scheduling next-f A-phase into MFMA-phase
// gaps. Fix: keep f's K/X entirely in registers; issue ALL f+1 loads after
// A-phase(f) but BEFORE the MFMA phase and the fence. Loads land during
// MFMA-phase(f); next A-phase pk ops (register-only, fence-transparent)
// become schedulable into its gaps. waves_per_eu(2) funds the +~48 VGPR of
// in-flight staging (occupancy stays LDS-pinned at 2.5 w/SIMD -- R19
// proved that dimension free). MFMA phase: R21 per-g form (R22 batch was
// neutral-negative).
// Discriminators: VGPR 44 -> ~90-120 (pipeline engaged); absmax EXACTLY
// 0.25; if load-wall theory right: main 33-37us; if flat ~42 with no
// spills: intra-f chain is the floor -> declare next round. WRITE_SIZE
// ~1MB (spill tripwire); FETCH ~2710KB; Occupancy ~31 (LDS-pinned).
// ---------------------------------------------------------------------------
__global__ __launch_bounds__(128)
__attribute__((amdgpu_waves_per_eu(2)))
void tr_main23(const float* __restrict__ X,
               const unsigned* __restrict__ K3h,
               float* __restrict__ out) {
    const int tid  = threadIdx.x;
    const int w    = __builtin_amdgcn_readfirstlane(tid >> 6);  // wave id, SGPR
    const int lane = tid & 63;
    const int c    = lane & 15;
    const int q    = lane >> 4;
    const int u      = blockIdx.x & 63;               // u-minor (R3/R7-proven)
    const int bgroup = blockIdx.x >> 6;               // 0..63
    const int b0     = ((bgroup << 1) + w) * G;       // SGPR-computed

    __shared__ __attribute__((aligned(16))) char lds[2 * G * 2048];
    char* Nb0 = lds + w * (G * 2048);

    // identity B-frags for f=0: B[k=8q+j][n=c(+16)]; f16 1.0 = 0x3C00 exact
    f16x8 idf0, idf1;
#pragma unroll
    for (int jj = 0; jj < 8; ++jj) {
        idf0[jj] = (8 * q + jj == c) ? (_Float16)1.0f : (_Float16)0.0f;
        idf1[jj] = (8 * q + jj == 16 + c) ? (_Float16)1.0f : (_Float16)0.0f;
    }

    const unsigned* Kt = K3h + ((size_t)u << 14) + (q << 9) + (c << 2);
    const f32x4 z = {0.f, 0.f, 0.f, 0.f};

    // ---- prologue: prefetch ALL f=0 operands into registers ----
    u32x4 kw[8];                  // K words for current f: kw[2jp], kw[2jp+1]
    f32x4 xvv[G];                 // X vectors for current f
#pragma unroll
    for (int jp = 0; jp < 4; ++jp) {
        kw[2 * jp]     = *(const u32x4*)(Kt + (jp << 7));
        kw[2 * jp + 1] = *(const u32x4*)(Kt + (jp << 7) + 64);
    }
#pragma unroll
    for (int g = 0; g < G; ++g)
        xvv[g] = *(const f32x4*)(X + ((b0 + g) << 5));

#pragma unroll
    for (int f = 0; f < NF; ++f) {
        // ---- X pack (VALU on prefetched registers; proven pkrtz+rfl) ----
        unsigned xdd[G][4];
#pragma unroll
        for (int g = 0; g < G; ++g)
#pragma unroll
            for (int d = 0; d < 4; ++d)
                xdd[g][d] = rfl_u(pkrtz(xvv[g][d], xvv[g][d]));

        // ---- A-phase: pure VALU from kw registers (no loads inside) ----
        u32x4 A0u[G], A1u[G];
#pragma unroll
        for (int jp = 0; jp < 4; ++jp) {
            const u32x4 c0 = kw[2 * jp], c1 = kw[2 * jp + 1];
#pragma unroll
            for (int g = 0; g < G; ++g) {
                {   // I = 0: A-word = (T[e_par0], T[e_par1]) f16
                    unsigned tv = pkmul_h(c0[0], xdd[g][0]);
                    tv = pkfma_h(c0[1], xdd[g][1], tv);
                    tv = pkfma_h(c0[2], xdd[g][2], tv);
                    tv = pkfma_h(c0[3], xdd[g][3], tv);
                    A0u[g][jp] = tv;
                }
                {   // I = 1
                    unsigned tv = pkmul_h(c1[0], xdd[g][0]);
                    tv = pkfma_h(c1[1], xdd[g][1], tv);
                    tv = pkfma_h(c1[2], xdd[g][2], tv);
                    tv = pkfma_h(c1[3], xdd[g][3], tv);
                    A1u[g][jp] = tv;
                }
            }
        }

        // ---- issue ALL f+1 loads now: BEFORE the MFMA phase and BEFORE
        //      the fence. They land during MFMA-phase(f); vmcnt wait sits
        //      at first use (next f's A-phase/X-pack). ----
        u32x4 kwn[8];
        f32x4 xvn[G];
        if (f < NF - 1) {
            const unsigned* Kn = Kt + ((f + 1) << 11);
#pragma unroll
            for (int jp = 0; jp < 4; ++jp) {
                kwn[2 * jp]     = *(const u32x4*)(Kn + (jp << 7));
                kwn[2 * jp + 1] = *(const u32x4*)(Kn + (jp << 7) + 64);
            }
#pragma unroll
            for (int g = 0; g < G; ++g)
                xvn[g] = *(const f32x4*)(X + ((b0 + g) << 5) + ((f + 1) << 2));
        }

        // ---- MFMA phase per g (R21 form, unchanged) ----
#pragma unroll
        for (int g = 0; g < G; ++g) {
            char* nb = Nb0 + (g << 11);
            f16x8 A0 = __builtin_bit_cast(f16x8, A0u[g]);
            f16x8 A1 = __builtin_bit_cast(f16x8, A1u[g]);

            f16x8 bf0, bf1;
            if (f == 0) { bf0 = idf0; bf1 = idf1; }
            else {
                bf0 = *(const f16x8*)(nb + (((q << 5) | c) << 4));
                bf1 = *(const f16x8*)(nb + (((q << 5) | c) << 4) + 256);
            }

            if (f < NF - 1) {
                f32x4 c00 = __builtin_amdgcn_mfma_f32_16x16x32_f16(A0, bf0, z, 0, 0, 0);
                f32x4 c01 = __builtin_amdgcn_mfma_f32_16x16x32_f16(A0, bf1, z, 0, 0, 0);
                f32x4 c10 = __builtin_amdgcn_mfma_f32_16x16x32_f16(A1, bf0, z, 0, 0, 0);
                f32x4 c11 = __builtin_amdgcn_mfma_f32_16x16x32_f16(A1, bf1, z, 0, 0, 0);
                // writeback N' (f16) for next f
#pragma unroll
                for (int I = 0; I < 2; ++I)
#pragma unroll
                    for (int J = 0; J < 2; ++J) {
                        f32x4 a = (I == 0) ? (J == 0 ? c00 : c01)
                                           : (J == 0 ? c10 : c11);
                        unsigned lo = pkrtz(a[0], a[1]);
                        unsigned hi = pkrtz(a[2], a[3]);
                        uint2 val; val.x = lo; val.y = hi;
                        // slot(p = 2I + (q>>1), n = 16J + c), byte +8*(q&1)
                        *(uint2*)(nb + (((((I << 1) | (q >> 1)) << 5) | (J << 4) | c) << 4)
                                     + ((q & 1) << 3)) = val;
                    }
            } else {
                // last step: only diagonal tiles feed the trace
                f32x4 c00 = __builtin_amdgcn_mfma_f32_16x16x32_f16(A0, bf0, z, 0, 0, 0);
                f32x4 c11 = __builtin_amdgcn_mfma_f32_16x16x32_f16(A1, bf1, z, 0, 0, 0);
                f32x4 t4 = c00 + c11;
                int ri = c & 3;
                float s = (ri == 0) ? t4[0] : (ri == 1) ? t4[1]
                        : (ri == 2) ? t4[2] : t4[3];
                s = ((c >> 2) == q) ? s : 0.f;
#pragma unroll
                for (int m = 32; m >= 1; m >>= 1) s += __shfl_xor(s, m, 64);
                if (lane == 0) out[((b0 + g) << 6) + u] = s;
            }
        }
        // Compiler memory fence: this-f LDS writes must precede next-f LDS
        // reads in program order (HW DS pipe is in-order per wave; only the
        // compiler could break it). The f+1 global loads were issued ABOVE
        // this fence by design; register-only pk ops pass through freely.
        asm volatile("" ::: "memory");

        // register rename (full unroll -> no instructions emitted)
        if (f < NF - 1) {
#pragma unroll
            for (int i = 0; i < 8; ++i) kw[i] = kwn[i];
#pragma unroll
            for (int g = 0; g < G; ++g) xvv[g] = xvn[g];
        }
    }
}

extern "C" void kernel_launch(void* const* d_in, const int* in_sizes, int n_in,
                              void* d_out, int out_size, void* d_ws, size_t ws_size,
                              hipStream_t stream) {
    (void)in_sizes; (void)n_in; (void)out_size; (void)ws_size;
    const float* X = (const float*)d_in[0];   // [512][8][4]
    const float* K = (const float*)d_in[1];   // [4][32][32][8][64]
    float* out = (float*)d_out;               // [512][64]
    unsigned* K3h = (unsigned*)d_ws;          // 4 MB, f16 par-pair words

    hipLaunchKernelGGL(tr_k3h23, dim3(512), dim3(256), 0, stream, K, K3h);
    hipLaunchKernelGGL(tr_main23, dim3(4096), dim3(128), 0, stream, X, K3h, out);
}